// Round 4
// baseline (1093.224 us; speedup 1.0000x reference)
//
#include <hip/hip_runtime.h>
#include <cmath>

#define NN   1000
#define TT   4
#define PP   10
#define DD   13
#define FF   128
#define HH   128
#define EAA  16
#define KDIM 64
#define EE   20000
#define I_NODE 91
#define I_EDGE 169
#define MROW  13000            // N*D
#define ROW4  3250             // MROW/4

// ---- workspace layout (floats) --------------------------------------------
// eblk  [0 .. 3,380,000)   E*169   (written D4, read D5)  — aliases m/agg:
//   m_buf [0 .. 128,000)           (live D1-D2)
//   agg   [128,000 .. 256,000)     (live D1-D3)
// nblk  [3,380,000 .. 3,549,000)   N*169 (written D3, read D5)
// V1    [3,549,000 .. 3,677,000)
// V2    [3,677,000 .. 3,805,000)
// U     [3,805,000 .. 3,933,000)
// Wcomb [3,933,000 .. 4,041,160)
// Wnc   [4,041,160 .. 4,127,688)
// ints  [4,127,688 ..):  cnt[1000], off[1001], cur[1000], adj[40000]
#define WS_EBLK  0L
#define WS_M     0L
#define WS_AGG   128000L
#define WS_NBLK  3380000L
#define WS_V1    3549000L
#define WS_V2    3677000L
#define WS_U     3805000L
#define WS_WCOMB 3933000L
#define WS_WNC   4041160L
#define WS_INT   4127688L
#define IO_CNT   0
#define IO_OFF   1000
#define IO_CUR   2001
#define IO_ADJ   3001

// ---- D1 "front": combs + node_msg + cnt-zero, one dispatch ----------------
#define NB_CE   640
#define NB_CN   512
#define NB_MSG  1000
#define NB_FRONT (NB_CE + NB_CN + NB_MSG + 1)

__global__ __launch_bounds__(256) void k_front(
    const float* __restrict__ We, const float* __restrict__ cobE,
    const float* __restrict__ Wn, const float* __restrict__ cobN,
    const float* __restrict__ nf, const float* __restrict__ Wmsg,
    float* __restrict__ Wcomb, float* __restrict__ Wnc,
    float* __restrict__ m, float* __restrict__ agg, int* __restrict__ cnt) {
  int b = blockIdx.x, t = threadIdx.x;
  if (b < NB_CE) {                       // comb_edge: Wcomb[p][k] = W_edge[p][k] @ cob_edge[p]
    if (t < I_EDGE) {
      int pk = b, p = pk >> 6;
      float acc = 0.f;
      const float* wrow = We + pk * I_EDGE;
      const float* crow = cobE + p * I_EDGE * I_EDGE + t;
      for (int i = 0; i < I_EDGE; ++i) acc += wrow[i] * crow[i * I_EDGE];
      Wcomb[pk * I_EDGE + t] = acc;
    }
  } else if (b < NB_CE + NB_CN) {        // comb_node
    if (t < I_EDGE) {
      int tf = b - NB_CE, ty = tf >> 7;
      float acc = 0.f;
      const float* wrow = Wn + tf * I_NODE;
      const float* crow = cobN + ty * I_NODE * I_EDGE + t;
      for (int i = 0; i < I_NODE; ++i) acc += wrow[i] * crow[i * I_EDGE];
      Wnc[tf * I_EDGE + t] = acc;
    }
  } else if (b < NB_CE + NB_CN + NB_MSG) {  // node_msg + agg zero
    int n = b - (NB_CE + NB_CN);
    __shared__ float row[FF];
    if (t < FF) row[t] = nf[n * FF + t];
    __syncthreads();
    if (t < FF) {
      float acc = 0.f;
#pragma unroll 8
      for (int f = 0; f < FF; ++f) acc += row[f] * Wmsg[f * FF + t];
      m[n * FF + t] = acc;
    } else {
      agg[n * FF + (t - FF)] = 0.f;
    }
  } else {                               // zero degree counters
    for (int i = t; i < NN; i += 256) cnt[i] = 0;
  }
}

// ---- D2: symmetric segment sum (agg atomics) + degree counting ------------
__global__ __launch_bounds__(256) void k_scatter(
    const float* __restrict__ m, const int* __restrict__ src,
    const int* __restrict__ dst, float* __restrict__ agg,
    int* __restrict__ cnt) {
  int idx = blockIdx.x * 256 + threadIdx.x;
  if (idx >= EE * FF) return;
  int e = idx >> 7, j = idx & 127;
  int s = src[e], d = dst[e];
  if (j == 0) { atomicAdd(&cnt[s], 1); atomicAdd(&cnt[d], 1); }
  atomicAdd(&agg[d * FF + j], m[s * FF + j]);
  atomicAdd(&agg[s * FF + j], m[d * FF + j]);
}

// ---- D3: node_h -> (V1,V2,U) precomputes + nblk; spare block = CSR prefix --
__global__ __launch_bounds__(192) void k_nodes(
    const float* __restrict__ nf, const float* __restrict__ agg,
    const float* __restrict__ na, const float* __restrict__ Wattr,
    const float* __restrict__ Wem, const float* __restrict__ Wproj,
    const int* __restrict__ ntype, const float* __restrict__ Wnc,
    float* __restrict__ V1, float* __restrict__ V2, float* __restrict__ U,
    float* __restrict__ nblk, const int* __restrict__ cnt,
    int* __restrict__ off, int* __restrict__ cur) {
  int t = threadIdx.x;
  if (blockIdx.x == NN) {                 // exclusive prefix scan of cnt[1000]
    __shared__ int sc[192];
    int base = t * 6, run = 0, loc[6];
#pragma unroll
    for (int i = 0; i < 6; ++i) {
      int v = (base + i < NN) ? cnt[base + i] : 0;
      loc[i] = run; run += v;
    }
    sc[t] = run;
    __syncthreads();
    for (int dd = 1; dd < 192; dd <<= 1) {
      int v = (t >= dd) ? sc[t - dd] : 0;
      __syncthreads();
      sc[t] += v;
      __syncthreads();
    }
    int excl = (t == 0) ? 0 : sc[t - 1];
#pragma unroll
    for (int i = 0; i < 6; ++i)
      if (base + i < NN) { int o = excl + loc[i]; off[base + i] = o; cur[base + i] = o; }
    if (t == 0) off[NN] = sc[191];
    return;
  }
  int n = blockIdx.x;
  int ty = ntype[n];
  __shared__ float row[FF];
  if (t < FF) {
    float a = 0.f;
#pragma unroll
    for (int q = 0; q < TT; ++q) a += na[n * TT + q] * Wattr[q * FF + t];
    row[t] = nf[n * FF + t] + agg[n * FF + t] * (1.0f / 20.0f) + a;
  }
  __syncthreads();
  if (t < FF) {
    float v1 = 0.f, v2 = 0.f;
#pragma unroll 4
    for (int f = 0; f < FF; ++f) {
      float x = row[f];
      v1 += x * Wem[f * HH + t];
      v2 += x * Wem[(FF + f) * HH + t];
    }
    V1[n * HH + t] = v1;
    V2[n * HH + t] = v2;
    int k = t & 63, half = t >> 6;
    const float* W = Wproj + (FF + half * FF) * KDIM + k;
    float u = 0.f;
#pragma unroll 4
    for (int f = 0; f < FF; ++f) u += row[f] * W[f * KDIM];
    U[n * 128 + t] = u;
  }
  if (t < I_EDGE) {
    float acc = 0.f;
    const float* W = Wnc + ty * FF * I_EDGE + t;
#pragma unroll 4
    for (int f = 0; f < FF; ++f) acc += row[f] * W[f * I_EDGE];
    nblk[n * I_EDGE + t] = acc;           // no atomics — assembled later
  }
}

// ---- D4: fused edge pipeline -> eblk (no atomics) + CSR fill, 4 edges/blk --
#define EB 4
__global__ __launch_bounds__(768) void k_edge_all(
    const float* __restrict__ V1, const float* __restrict__ V2,
    const float* __restrict__ U, const float* __restrict__ ef,
    const float* __restrict__ ea, const int* __restrict__ src,
    const int* __restrict__ dst, const int* __restrict__ etype,
    const float* __restrict__ Wem, const float* __restrict__ Wproj,
    const float* __restrict__ Wcomb, float* __restrict__ eblk,
    int* __restrict__ cur, int* __restrict__ adj) {
  int t = threadIdx.x;      // 0..191
  int ei = threadIdx.y;     // 0..3
  int e = blockIdx.x * EB + ei;
  int s = src[e], d = dst[e], p = etype[e];
  __shared__ __align__(16) float efa[EB][32];
  __shared__ __align__(16) float em[EB][HH];
  __shared__ __align__(16) float hp[EB][2][KDIM];
  __shared__ __align__(16) float h[EB][2][KDIM];
  __shared__ __align__(16) float tji[EB][I_EDGE];

  if (t == 0) {             // CSR fill (one lane per edge)
    int pos = atomicAdd(&cur[s], 1); adj[pos] = 2 * e;
    int pos2 = atomicAdd(&cur[d], 1); adj[pos2] = 2 * e + 1;
  }
  if (t < 32) efa[ei][t] = (t < 16) ? ef[e * EAA + t] : ea[e * EAA + (t - 16)];
  __syncthreads();

  if (t < HH) {             // edge message
    float acc = V1[s * HH + t] + V2[d * HH + t];
#pragma unroll
    for (int c = 0; c < 32; ++c) acc += efa[ei][c] * Wem[(256 + c) * HH + t];
    em[ei][t] = tanhf(acc);
  }
  __syncthreads();

  if (t < 128) {            // msg projection, split over f-halves
    int k = t & 63, half = t >> 6;
    float hm = 0.f;
    for (int f = half * 64; f < half * 64 + 64; f += 4) {
      float4 mv = *(const float4*)&em[ei][f];
      hm += mv.x * Wproj[(f + 0) * KDIM + k] + mv.y * Wproj[(f + 1) * KDIM + k]
          + mv.z * Wproj[(f + 2) * KDIM + k] + mv.w * Wproj[(f + 3) * KDIM + k];
    }
    hp[ei][half][k] = hm;
  }
  __syncthreads();
  if (t < KDIM) {           // h build (both orientations)
    float hm = hp[ei][0][t] + hp[ei][1][t];
    h[ei][0][t] = hm + U[s * 128 + t] + U[d * 128 + 64 + t];
    h[ei][1][t] = hm + U[d * 128 + t] + U[s * 128 + 64 + t];
  }
  __syncthreads();

  float bij = 0.f, bji = 0.f;
  if (t < I_EDGE) {
    const float* W = Wcomb + p * KDIM * I_EDGE + t;
    for (int k = 0; k < KDIM; k += 4) {
      float4 hi = *(const float4*)&h[ei][0][k];
      float4 hj = *(const float4*)&h[ei][1][k];
      float w0 = W[(k + 0) * I_EDGE], w1 = W[(k + 1) * I_EDGE];
      float w2 = W[(k + 2) * I_EDGE], w3 = W[(k + 3) * I_EDGE];
      bij += hi.x * w0 + hi.y * w1 + hi.z * w2 + hi.w * w3;
      bji += hj.x * w0 + hj.y * w1 + hj.z * w2 + hj.w * w3;
    }
    tji[ei][t] = bji;
  }
  __syncthreads();
  if (t < I_EDGE) {
    int x = t / DD, y = t % DD;
    eblk[(size_t)e * I_EDGE + t] = 0.5f * (bij + tji[ei][y * DD + x]);
  }
}

// ---- D5: assemble M — each block exclusively owns one 13-row strip ---------
// zero the strip (float4), barrier, then serially += nblk + incident eblk.
// Same thread owns the same (x,y) for every addend -> no races, no atomics.
__global__ __launch_bounds__(256) void k_assemble(
    const float* __restrict__ eblk, const float* __restrict__ nblk,
    const int* __restrict__ off, const int* __restrict__ adj,
    const int* __restrict__ src, const int* __restrict__ dst,
    float* __restrict__ M) {
  int n = blockIdx.x, t = threadIdx.x;
  float4* M4 = (float4*)M;
  // phase 1: zero rows n*13 .. n*13+12
  const float4 z = make_float4(0.f, 0.f, 0.f, 0.f);
  for (int i = t; i < DD * ROW4; i += 256) {
    int r = n * DD + i / ROW4;
    M4[(size_t)r * ROW4 + (i % ROW4)] = z;
  }
  __threadfence_block();
  __syncthreads();
  // phase 2: accumulate blocks (exclusive row ownership -> plain +=)
  if (t < I_EDGE) {
    int x = t / DD, y = t % DD;
    size_t rb = (size_t)(n * DD + x) * MROW;
    M[rb + n * DD + y] += nblk[n * I_EDGE + t];
    int o0 = off[n], o1 = off[n + 1];
    for (int idx = o0; idx < o1; ++idx) {
      int entry = adj[idx];
      int e = entry >> 1, dir = entry & 1;
      int other = dir ? src[e] : dst[e];
      float v = dir ? eblk[(size_t)e * I_EDGE + y * DD + x]
                    : eblk[(size_t)e * I_EDGE + t];
      M[rb + other * DD + y] += v;
    }
  }
}

extern "C" void kernel_launch(void* const* d_in, const int* in_sizes, int n_in,
                              void* d_out, int out_size, void* d_ws, size_t ws_size,
                              hipStream_t stream) {
  const float* node_feats = (const float*)d_in[0];
  const float* node_attrs = (const float*)d_in[1];
  const float* edge_feats = (const float*)d_in[2];
  const float* edge_attrs = (const float*)d_in[3];
  const int*   edge_index = (const int*)d_in[4];
  const int*   node_types = (const int*)d_in[5];
  const int*   edge_types = (const int*)d_in[6];
  const float* W_msg  = (const float*)d_in[7];
  const float* W_attr = (const float*)d_in[8];
  const float* W_em   = (const float*)d_in[9];
  const float* W_proj = (const float*)d_in[10];
  const float* W_node = (const float*)d_in[11];
  const float* W_edge = (const float*)d_in[12];
  const float* cob_node = (const float*)d_in[13];
  const float* cob_edge = (const float*)d_in[14];

  float* M  = (float*)d_out;
  float* ws = (float*)d_ws;
  float* eblk  = ws + WS_EBLK;
  float* m_buf = ws + WS_M;       // aliases eblk head (dead before D4)
  float* agg   = ws + WS_AGG;     // aliases eblk (dead before D4)
  float* nblk  = ws + WS_NBLK;
  float* V1    = ws + WS_V1;
  float* V2    = ws + WS_V2;
  float* U     = ws + WS_U;
  float* Wcomb = ws + WS_WCOMB;
  float* Wnc   = ws + WS_WNC;
  int*   iw    = (int*)(ws + WS_INT);
  int*   cnt   = iw + IO_CNT;
  int*   off   = iw + IO_OFF;
  int*   cur   = iw + IO_CUR;
  int*   adj   = iw + IO_ADJ;

  const int* src = edge_index;        // edge_index[0]
  const int* dst = edge_index + EE;   // edge_index[1]

  k_front   <<<NB_FRONT, 256, 0, stream>>>(W_edge, cob_edge, W_node, cob_node,
                                           node_feats, W_msg, Wcomb, Wnc,
                                           m_buf, agg, cnt);
  k_scatter <<<(EE * FF) / 256, 256, 0, stream>>>(m_buf, src, dst, agg, cnt);
  k_nodes   <<<NN + 1, 192, 0, stream>>>(node_feats, agg, node_attrs, W_attr,
                                         W_em, W_proj, node_types, Wnc,
                                         V1, V2, U, nblk, cnt, off, cur);
  k_edge_all<<<dim3(EE / EB), dim3(192, 4), 0, stream>>>(V1, V2, U, edge_feats,
                                                         edge_attrs, src, dst,
                                                         edge_types, W_em, W_proj,
                                                         Wcomb, eblk, cur, adj);
  k_assemble<<<NN, 256, 0, stream>>>(eblk, nblk, off, adj, src, dst, M);
}

// Round 5
// 953.973 us; speedup vs baseline: 1.1460x; 1.1460x over previous
//
#include <hip/hip_runtime.h>
#include <cmath>

#define NN   1000
#define TT   4
#define PP   10
#define DD   13
#define FF   128
#define HH   128
#define EAA  16
#define KDIM 64
#define EE   20000
#define I_NODE 91
#define I_EDGE 169
#define MROW  13000            // N*D
#define ROW4  3250             // MROW/4

// ---- workspace layout (floats) --------------------------------------------
#define WS_EBLK  0L
#define WS_M     0L
#define WS_AGG   128000L
#define WS_NBLK  3380000L
#define WS_V1    3549000L
#define WS_V2    3677000L
#define WS_U     3805000L
#define WS_WCOMB 3933000L
#define WS_WNC   4041160L
#define WS_INT   4127688L
#define IO_CNT   0
#define IO_OFF   1000
#define IO_CUR   2001
#define IO_ADJ   3001

// ---- D1 "front": combs + node_msg + cnt-zero, one dispatch ----------------
#define NB_CE   640
#define NB_CN   512
#define NB_MSG  1000
#define NB_FRONT (NB_CE + NB_CN + NB_MSG + 1)

__global__ __launch_bounds__(256) void k_front(
    const float* __restrict__ We, const float* __restrict__ cobE,
    const float* __restrict__ Wn, const float* __restrict__ cobN,
    const float* __restrict__ nf, const float* __restrict__ Wmsg,
    float* __restrict__ Wcomb, float* __restrict__ Wnc,
    float* __restrict__ m, float* __restrict__ agg, int* __restrict__ cnt) {
  int b = blockIdx.x, t = threadIdx.x;
  if (b < NB_CE) {                       // comb_edge
    if (t < I_EDGE) {
      int pk = b, p = pk >> 6;
      float acc = 0.f;
      const float* wrow = We + pk * I_EDGE;
      const float* crow = cobE + p * I_EDGE * I_EDGE + t;
      for (int i = 0; i < I_EDGE; ++i) acc += wrow[i] * crow[i * I_EDGE];
      Wcomb[pk * I_EDGE + t] = acc;
    }
  } else if (b < NB_CE + NB_CN) {        // comb_node
    if (t < I_EDGE) {
      int tf = b - NB_CE, ty = tf >> 7;
      float acc = 0.f;
      const float* wrow = Wn + tf * I_NODE;
      const float* crow = cobN + ty * I_NODE * I_EDGE + t;
      for (int i = 0; i < I_NODE; ++i) acc += wrow[i] * crow[i * I_EDGE];
      Wnc[tf * I_EDGE + t] = acc;
    }
  } else if (b < NB_CE + NB_CN + NB_MSG) {  // node_msg + agg zero
    int n = b - (NB_CE + NB_CN);
    __shared__ float row[FF];
    if (t < FF) row[t] = nf[n * FF + t];
    __syncthreads();
    if (t < FF) {
      float acc = 0.f;
#pragma unroll 8
      for (int f = 0; f < FF; ++f) acc += row[f] * Wmsg[f * FF + t];
      m[n * FF + t] = acc;
    } else {
      agg[n * FF + (t - FF)] = 0.f;
    }
  } else {                               // zero degree counters
    for (int i = t; i < NN; i += 256) cnt[i] = 0;
  }
}

// ---- D2: symmetric segment sum (agg atomics) + degree counting ------------
__global__ __launch_bounds__(256) void k_scatter(
    const float* __restrict__ m, const int* __restrict__ src,
    const int* __restrict__ dst, float* __restrict__ agg,
    int* __restrict__ cnt) {
  int idx = blockIdx.x * 256 + threadIdx.x;
  if (idx >= EE * FF) return;
  int e = idx >> 7, j = idx & 127;
  int s = src[e], d = dst[e];
  if (j == 0) { atomicAdd(&cnt[s], 1); atomicAdd(&cnt[d], 1); }
  atomicAdd(&agg[d * FF + j], m[s * FF + j]);
  atomicAdd(&agg[s * FF + j], m[d * FF + j]);
}

// ---- D3: node_h -> (V1,V2,U) precomputes + nblk; spare block = CSR prefix --
__global__ __launch_bounds__(192) void k_nodes(
    const float* __restrict__ nf, const float* __restrict__ agg,
    const float* __restrict__ na, const float* __restrict__ Wattr,
    const float* __restrict__ Wem, const float* __restrict__ Wproj,
    const int* __restrict__ ntype, const float* __restrict__ Wnc,
    float* __restrict__ V1, float* __restrict__ V2, float* __restrict__ U,
    float* __restrict__ nblk, const int* __restrict__ cnt,
    int* __restrict__ off, int* __restrict__ cur) {
  int t = threadIdx.x;
  if (blockIdx.x == NN) {                 // exclusive prefix scan of cnt[1000]
    __shared__ int sc[192];
    int base = t * 6, run = 0, loc[6];
#pragma unroll
    for (int i = 0; i < 6; ++i) {
      int v = (base + i < NN) ? cnt[base + i] : 0;
      loc[i] = run; run += v;
    }
    sc[t] = run;
    __syncthreads();
    for (int dd = 1; dd < 192; dd <<= 1) {
      int v = (t >= dd) ? sc[t - dd] : 0;
      __syncthreads();
      sc[t] += v;
      __syncthreads();
    }
    int excl = (t == 0) ? 0 : sc[t - 1];
#pragma unroll
    for (int i = 0; i < 6; ++i)
      if (base + i < NN) { int o = excl + loc[i]; off[base + i] = o; cur[base + i] = o; }
    if (t == 0) off[NN] = sc[191];
    return;
  }
  int n = blockIdx.x;
  int ty = ntype[n];
  __shared__ float row[FF];
  if (t < FF) {
    float a = 0.f;
#pragma unroll
    for (int q = 0; q < TT; ++q) a += na[n * TT + q] * Wattr[q * FF + t];
    row[t] = nf[n * FF + t] + agg[n * FF + t] * (1.0f / 20.0f) + a;
  }
  __syncthreads();
  if (t < FF) {
    float v1 = 0.f, v2 = 0.f;
#pragma unroll 4
    for (int f = 0; f < FF; ++f) {
      float x = row[f];
      v1 += x * Wem[f * HH + t];
      v2 += x * Wem[(FF + f) * HH + t];
    }
    V1[n * HH + t] = v1;
    V2[n * HH + t] = v2;
    int k = t & 63, half = t >> 6;
    const float* W = Wproj + (FF + half * FF) * KDIM + k;
    float u = 0.f;
#pragma unroll 4
    for (int f = 0; f < FF; ++f) u += row[f] * W[f * KDIM];
    U[n * 128 + t] = u;
  }
  if (t < I_EDGE) {
    float acc = 0.f;
    const float* W = Wnc + ty * FF * I_EDGE + t;
#pragma unroll 4
    for (int f = 0; f < FF; ++f) acc += row[f] * W[f * I_EDGE];
    nblk[n * I_EDGE + t] = acc;           // no atomics — assembled later
  }
}

// ---- D4: fused edge pipeline -> eblk (no atomics) + CSR fill, 4 edges/blk --
#define EB 4
__global__ __launch_bounds__(768) void k_edge_all(
    const float* __restrict__ V1, const float* __restrict__ V2,
    const float* __restrict__ U, const float* __restrict__ ef,
    const float* __restrict__ ea, const int* __restrict__ src,
    const int* __restrict__ dst, const int* __restrict__ etype,
    const float* __restrict__ Wem, const float* __restrict__ Wproj,
    const float* __restrict__ Wcomb, float* __restrict__ eblk,
    int* __restrict__ cur, int* __restrict__ adj) {
  int t = threadIdx.x;      // 0..191
  int ei = threadIdx.y;     // 0..3
  int e = blockIdx.x * EB + ei;
  int s = src[e], d = dst[e], p = etype[e];
  __shared__ __align__(16) float efa[EB][32];
  __shared__ __align__(16) float em[EB][HH];
  __shared__ __align__(16) float hp[EB][2][KDIM];
  __shared__ __align__(16) float h[EB][2][KDIM];
  __shared__ __align__(16) float tji[EB][I_EDGE];

  if (t == 0) {             // CSR fill (one lane per edge)
    int pos = atomicAdd(&cur[s], 1); adj[pos] = 2 * e;
    int pos2 = atomicAdd(&cur[d], 1); adj[pos2] = 2 * e + 1;
  }
  if (t < 32) efa[ei][t] = (t < 16) ? ef[e * EAA + t] : ea[e * EAA + (t - 16)];
  __syncthreads();

  if (t < HH) {             // edge message
    float acc = V1[s * HH + t] + V2[d * HH + t];
#pragma unroll
    for (int c = 0; c < 32; ++c) acc += efa[ei][c] * Wem[(256 + c) * HH + t];
    em[ei][t] = tanhf(acc);
  }
  __syncthreads();

  if (t < 128) {            // msg projection, split over f-halves
    int k = t & 63, half = t >> 6;
    float hm = 0.f;
    for (int f = half * 64; f < half * 64 + 64; f += 4) {
      float4 mv = *(const float4*)&em[ei][f];
      hm += mv.x * Wproj[(f + 0) * KDIM + k] + mv.y * Wproj[(f + 1) * KDIM + k]
          + mv.z * Wproj[(f + 2) * KDIM + k] + mv.w * Wproj[(f + 3) * KDIM + k];
    }
    hp[ei][half][k] = hm;
  }
  __syncthreads();
  if (t < KDIM) {           // h build (both orientations)
    float hm = hp[ei][0][t] + hp[ei][1][t];
    h[ei][0][t] = hm + U[s * 128 + t] + U[d * 128 + 64 + t];
    h[ei][1][t] = hm + U[d * 128 + t] + U[s * 128 + 64 + t];
  }
  __syncthreads();

  float bij = 0.f, bji = 0.f;
  if (t < I_EDGE) {
    const float* W = Wcomb + p * KDIM * I_EDGE + t;
    for (int k = 0; k < KDIM; k += 4) {
      float4 hi = *(const float4*)&h[ei][0][k];
      float4 hj = *(const float4*)&h[ei][1][k];
      float w0 = W[(k + 0) * I_EDGE], w1 = W[(k + 1) * I_EDGE];
      float w2 = W[(k + 2) * I_EDGE], w3 = W[(k + 3) * I_EDGE];
      bij += hi.x * w0 + hi.y * w1 + hi.z * w2 + hi.w * w3;
      bji += hj.x * w0 + hj.y * w1 + hj.z * w2 + hj.w * w3;
    }
    tji[ei][t] = bji;
  }
  __syncthreads();
  if (t < I_EDGE) {
    int x = t / DD, y = t % DD;
    eblk[(size_t)e * I_EDGE + t] = 0.5f * (bij + tji[ei][y * DD + x]);
  }
}

// ---- D5: assemble M — LDS-accumulate per strip, then ONE streaming pass ----
// Each block owns rows [n*13, n*13+13). Blocks gather their ~41 incident
// 13x13 blocks into LDS (slot map per column, int8), then write the whole
// strip with pure float4 stores: no zero-pass, no RMW, no atomics on M.
// Block columns are 13-aligned => col%13 is the offset inside a block.
#define MAXS 72
__global__ __launch_bounds__(256) void k_assemble(
    const float* __restrict__ eblk, const float* __restrict__ nblk,
    const int* __restrict__ off, const int* __restrict__ adj,
    const int* __restrict__ src, const int* __restrict__ dst,
    float* __restrict__ M) {
  int n = blockIdx.x, t = threadIdx.x;
  __shared__ float blk[MAXS][I_EDGE];
  __shared__ signed char map8[13008];
  __shared__ int s_ed[MAXS];
  __shared__ short s_other[MAXS];
  int* map32 = (int*)map8;
  for (int i = t; i < 3252; i += 256) map32[i] = -1;
  int o0 = off[n], o1 = off[n + 1];
  int nent = 1 + (o1 - o0);                // entry 0 = diagonal block
  int ns = nent < MAXS ? nent : MAXS;
  for (int i = t; i < ns; i += 256) {
    int ed, other;
    if (i == 0) { ed = -1; other = n; }
    else { ed = adj[o0 + i - 1]; int e = ed >> 1; other = (ed & 1) ? src[e] : dst[e]; }
    s_ed[i] = ed; s_other[i] = (short)other;
  }
  __syncthreads();
  // map fill: winner-takes-column among duplicate 'other' (races OK: only
  // entries with the same 'other' write the same bytes; any winner works)
  for (int j = t; j < ns * DD; j += 256) {
    int i = j / DD, c = j - i * DD;
    map8[(int)s_other[i] * DD + c] = (signed char)i;
  }
  // blk fill: independent, fully pipelined global loads
  for (int j = t; j < ns * I_EDGE; j += 256) {
    int i = j / I_EDGE, cell = j - i * I_EDGE;
    int ed = s_ed[i];
    float v;
    if (ed < 0)      v = nblk[n * I_EDGE + cell];
    else if (ed & 1) v = eblk[(size_t)(ed >> 1) * I_EDGE + (cell % DD) * DD + cell / DD];
    else             v = eblk[(size_t)(ed >> 1) * I_EDGE + cell];
    blk[i][cell] = v;
  }
  __syncthreads();
  // dedup: merge non-winning duplicates into each column's winner slot.
  // winner-per-column is unique => no read/write race on blk[i][cell].
  for (int j = t; j < ns * I_EDGE; j += 256) {
    int i = j / I_EDGE, cell = j - i * I_EDGE;
    int cloc = cell % DD;
    int w = map8[(int)s_other[i] * DD + cloc];
    if (w != i) atomicAdd(&blk[w][cell], blk[i][cell]);
  }
  __syncthreads();
  // phase B: stream the strip — one coalesced float4 store per element group
  float4* M4 = (float4*)M;
  for (int r = 0; r < DD; ++r) {
    float4* rowp = M4 + (size_t)(n * DD + r) * ROW4;
    int rb = r * DD;
    for (int c4 = t; c4 < ROW4; c4 += 256) {
      int mp = map32[c4];
      float4 v = make_float4(0.f, 0.f, 0.f, 0.f);
      if (mp != -1) {                       // rare (~5% of groups)
        int col = c4 * 4;
        signed char m0 = (signed char)(mp & 0xff);
        signed char m1 = (signed char)((mp >> 8) & 0xff);
        signed char m2 = (signed char)((mp >> 16) & 0xff);
        signed char m3 = (signed char)((mp >> 24) & 0xff);
        if (m0 >= 0) v.x = blk[m0][rb + (col + 0) % DD];
        if (m1 >= 0) v.y = blk[m1][rb + (col + 1) % DD];
        if (m2 >= 0) v.z = blk[m2][rb + (col + 2) % DD];
        if (m3 >= 0) v.w = blk[m3][rb + (col + 3) % DD];
      }
      rowp[c4] = v;
    }
  }
  // overflow (degree+1 > MAXS): exclusive-strip RMW after the streaming pass.
  // Unreachable for Poisson(40) degrees; kept for input-independence.
  if (nent > MAXS) {
    __threadfence_block();
    __syncthreads();
    if (t < I_EDGE) {
      int x = t / DD, y = t - (t / DD) * DD;
      for (int i = MAXS; i < nent; ++i) {
        int ed = adj[o0 + i - 1]; int e = ed >> 1;
        int other = (ed & 1) ? src[e] : dst[e];
        float v = (ed & 1) ? eblk[(size_t)e * I_EDGE + y * DD + x]
                           : eblk[(size_t)e * I_EDGE + x * DD + y];
        M[(size_t)(n * DD + x) * MROW + other * DD + y] += v;
      }
    }
  }
}

extern "C" void kernel_launch(void* const* d_in, const int* in_sizes, int n_in,
                              void* d_out, int out_size, void* d_ws, size_t ws_size,
                              hipStream_t stream) {
  const float* node_feats = (const float*)d_in[0];
  const float* node_attrs = (const float*)d_in[1];
  const float* edge_feats = (const float*)d_in[2];
  const float* edge_attrs = (const float*)d_in[3];
  const int*   edge_index = (const int*)d_in[4];
  const int*   node_types = (const int*)d_in[5];
  const int*   edge_types = (const int*)d_in[6];
  const float* W_msg  = (const float*)d_in[7];
  const float* W_attr = (const float*)d_in[8];
  const float* W_em   = (const float*)d_in[9];
  const float* W_proj = (const float*)d_in[10];
  const float* W_node = (const float*)d_in[11];
  const float* W_edge = (const float*)d_in[12];
  const float* cob_node = (const float*)d_in[13];
  const float* cob_edge = (const float*)d_in[14];

  float* M  = (float*)d_out;
  float* ws = (float*)d_ws;
  float* eblk  = ws + WS_EBLK;
  float* m_buf = ws + WS_M;       // aliases eblk head (dead before D4)
  float* agg   = ws + WS_AGG;     // aliases eblk (dead before D4)
  float* nblk  = ws + WS_NBLK;
  float* V1    = ws + WS_V1;
  float* V2    = ws + WS_V2;
  float* U     = ws + WS_U;
  float* Wcomb = ws + WS_WCOMB;
  float* Wnc   = ws + WS_WNC;
  int*   iw    = (int*)(ws + WS_INT);
  int*   cnt   = iw + IO_CNT;
  int*   off   = iw + IO_OFF;
  int*   cur   = iw + IO_CUR;
  int*   adj   = iw + IO_ADJ;

  const int* src = edge_index;        // edge_index[0]
  const int* dst = edge_index + EE;   // edge_index[1]

  k_front   <<<NB_FRONT, 256, 0, stream>>>(W_edge, cob_edge, W_node, cob_node,
                                           node_feats, W_msg, Wcomb, Wnc,
                                           m_buf, agg, cnt);
  k_scatter <<<(EE * FF) / 256, 256, 0, stream>>>(m_buf, src, dst, agg, cnt);
  k_nodes   <<<NN + 1, 192, 0, stream>>>(node_feats, agg, node_attrs, W_attr,
                                         W_em, W_proj, node_types, Wnc,
                                         V1, V2, U, nblk, cnt, off, cur);
  k_edge_all<<<dim3(EE / EB), dim3(192, 4), 0, stream>>>(V1, V2, U, edge_feats,
                                                         edge_attrs, src, dst,
                                                         edge_types, W_em, W_proj,
                                                         Wcomb, eblk, cur, adj);
  k_assemble<<<NN, 256, 0, stream>>>(eblk, nblk, off, adj, src, dst, M);
}

// Round 6
// 938.155 us; speedup vs baseline: 1.1653x; 1.0169x over previous
//
#include <hip/hip_runtime.h>
#include <cmath>

#define NN   1000
#define TT   4
#define PP   10
#define DD   13
#define FF   128
#define HH   128
#define EAA  16
#define KDIM 64
#define EE   20000
#define I_NODE 91
#define I_EDGE 169
#define MROW  13000            // N*D
#define ROW4  3250             // MROW/4

// ---- workspace layout (floats) --------------------------------------------
// m_buf [0..128,000)             D1 -> D5 (node gather)
// hmsg  [0..1,280,000)           D6 -> D7 (overlays m_buf; m dead after D5)
// nblk  [1,280,000..1,449,000)   D5 -> D8
// V1    [1,449,000..1,577,000)   D5 -> D6
// V2    [1,577,000..1,705,000)   D5 -> D6
// U     [1,705,000..1,833,000)   D5 -> D7
// Wcomb [1,833,000..1,941,160)   D1 -> D7
// Wnc   [1,941,160..2,027,688)   D1 -> D5
// INT   [2,027,688..2,070,689)   cnt[1000] off[1001] cur[1000] adj[40000]
// eblk  [2,070,696..5,450,696)   D7 -> D8   (~21.8 MB total)
#define WS_MBUF  0L
#define WS_HMSG  0L
#define WS_NBLK  1280000L
#define WS_V1    1449000L
#define WS_V2    1577000L
#define WS_U     1705000L
#define WS_WCOMB 1833000L
#define WS_WNC   1941160L
#define WS_INT   2027688L
#define WS_EBLK  2070696L
#define IO_CNT   0
#define IO_OFF   1000
#define IO_CUR   2001
#define IO_ADJ   3001

// ---- D1 "front": combs + node_msg + cnt-zero ------------------------------
#define NB_CE   640
#define NB_CN   512
#define NB_MSG  1000
#define NB_FRONT (NB_CE + NB_CN + NB_MSG + 1)

__global__ __launch_bounds__(256) void k_front(
    const float* __restrict__ We, const float* __restrict__ cobE,
    const float* __restrict__ Wn, const float* __restrict__ cobN,
    const float* __restrict__ nf, const float* __restrict__ Wmsg,
    float* __restrict__ Wcomb, float* __restrict__ Wnc,
    float* __restrict__ m, int* __restrict__ cnt) {
  int b = blockIdx.x, t = threadIdx.x;
  if (b < NB_CE) {                       // comb_edge: Wcomb[p][k] = W_edge[p][k] @ cob_edge[p]
    if (t < I_EDGE) {
      int pk = b, p = pk >> 6;
      float acc = 0.f;
      const float* wrow = We + pk * I_EDGE;
      const float* crow = cobE + p * I_EDGE * I_EDGE + t;
      for (int i = 0; i < I_EDGE; ++i) acc += wrow[i] * crow[i * I_EDGE];
      Wcomb[pk * I_EDGE + t] = acc;
    }
  } else if (b < NB_CE + NB_CN) {        // comb_node
    if (t < I_EDGE) {
      int tf = b - NB_CE, ty = tf >> 7;
      float acc = 0.f;
      const float* wrow = Wn + tf * I_NODE;
      const float* crow = cobN + ty * I_NODE * I_EDGE + t;
      for (int i = 0; i < I_NODE; ++i) acc += wrow[i] * crow[i * I_EDGE];
      Wnc[tf * I_EDGE + t] = acc;
    }
  } else if (b < NB_CE + NB_CN + NB_MSG) {  // node_msg
    int n = b - (NB_CE + NB_CN);
    __shared__ float row[FF];
    if (t < FF) row[t] = nf[n * FF + t];
    __syncthreads();
    if (t < FF) {
      float acc = 0.f;
#pragma unroll 8
      for (int f = 0; f < FF; ++f) acc += row[f] * Wmsg[f * FF + t];
      m[n * FF + t] = acc;
    }
  } else {                               // zero degree counters
    for (int i = t; i < NN; i += 256) cnt[i] = 0;
  }
}

// ---- D2: degree count (tiny; 40K atomics total) ---------------------------
__global__ __launch_bounds__(256) void k_count(
    const int* __restrict__ src, const int* __restrict__ dst,
    int* __restrict__ cnt) {
  int e = blockIdx.x * 256 + threadIdx.x;
  if (e >= EE) return;
  atomicAdd(&cnt[src[e]], 1);
  atomicAdd(&cnt[dst[e]], 1);
}

// ---- D3: exclusive prefix scan of cnt[1000] (one block) -------------------
__global__ __launch_bounds__(256) void k_scan(
    const int* __restrict__ cnt, int* __restrict__ off, int* __restrict__ cur) {
  int t = threadIdx.x;
  __shared__ int sc[256];
  int base = t * 4, run = 0, loc[4];
#pragma unroll
  for (int i = 0; i < 4; ++i) {
    int v = (base + i < NN) ? cnt[base + i] : 0;
    loc[i] = run; run += v;
  }
  sc[t] = run;
  __syncthreads();
  for (int dd = 1; dd < 256; dd <<= 1) {
    int v = (t >= dd) ? sc[t - dd] : 0;
    __syncthreads();
    sc[t] += v;
    __syncthreads();
  }
  int excl = (t == 0) ? 0 : sc[t - 1];
#pragma unroll
  for (int i = 0; i < 4; ++i)
    if (base + i < NN) { int o = excl + loc[i]; off[base + i] = o; cur[base + i] = o; }
  if (t == 0) off[NN] = sc[255];
}

// ---- D4: adjacency fill (tiny) --------------------------------------------
__global__ __launch_bounds__(256) void k_adj(
    const int* __restrict__ src, const int* __restrict__ dst,
    int* __restrict__ cur, int* __restrict__ adj) {
  int e = blockIdx.x * 256 + threadIdx.x;
  if (e >= EE) return;
  int p1 = atomicAdd(&cur[src[e]], 1); adj[p1] = 2 * e;
  int p2 = atomicAdd(&cur[dst[e]], 1); adj[p2] = 2 * e + 1;
}

// ---- D5: CSR-gather agg (no atomics) + node_h + V1/V2/U + nblk ------------
__global__ __launch_bounds__(192) void k_nodes(
    const float* __restrict__ nf, const float* __restrict__ m,
    const float* __restrict__ na, const float* __restrict__ Wattr,
    const float* __restrict__ Wem, const float* __restrict__ Wproj,
    const int* __restrict__ ntype, const float* __restrict__ Wnc,
    const int* __restrict__ off, const int* __restrict__ adj,
    const int* __restrict__ src, const int* __restrict__ dst,
    float* __restrict__ V1, float* __restrict__ V2, float* __restrict__ U,
    float* __restrict__ nblk) {
  int n = blockIdx.x, t = threadIdx.x;
  int ty = ntype[n];
  __shared__ float row[FF];
  if (t < FF) {
    float a = 0.f;
#pragma unroll
    for (int q = 0; q < TT; ++q) a += na[n * TT + q] * Wattr[q * FF + t];
    float g = 0.f;
    int o0 = off[n], o1 = off[n + 1];
    for (int o = o0; o < o1; ++o) {            // gather replaces atomics:
      int ed = adj[o];                         // agg[n] += m[other]
      int e = ed >> 1;
      int other = (ed & 1) ? src[e] : dst[e];
      g += m[other * FF + t];
    }
    row[t] = nf[n * FF + t] + g * (1.0f / 20.0f) + a;
  }
  __syncthreads();
  if (t < FF) {
    float v1 = 0.f, v2 = 0.f;
#pragma unroll 4
    for (int f = 0; f < FF; ++f) {
      float x = row[f];
      v1 += x * Wem[f * HH + t];
      v2 += x * Wem[(FF + f) * HH + t];
    }
    V1[n * HH + t] = v1;
    V2[n * HH + t] = v2;
    int k = t & 63, half = t >> 6;
    const float* W = Wproj + (FF + half * FF) * KDIM + k;
    float u = 0.f;
#pragma unroll 4
    for (int f = 0; f < FF; ++f) u += row[f] * W[f * KDIM];
    U[n * 128 + t] = u;
  }
  if (t < I_EDGE) {
    float acc = 0.f;
    const float* W = Wnc + ty * FF * I_EDGE + t;
#pragma unroll 4
    for (int f = 0; f < FF; ++f) acc += row[f] * W[f * I_EDGE];
    nblk[n * I_EDGE + t] = acc;
  }
}

// ---- D6: edge message + msg-projection (R2's proven kernel) ---------------
#define EPB 8
__global__ __launch_bounds__(128) void k_edge_msg(
    const float* __restrict__ V1, const float* __restrict__ V2,
    const float* __restrict__ ef, const float* __restrict__ ea,
    const int* __restrict__ src, const int* __restrict__ dst,
    const float* __restrict__ Wem, const float* __restrict__ Wproj,
    float* __restrict__ hmsg) {
  int e0 = blockIdx.x * EPB;
  int j = threadIdx.x;
  __shared__ float efa[EPB][32];
  __shared__ float em[EPB][HH];
  for (int i = j; i < EPB * 32; i += 128) {
    int e = i >> 5, c = i & 31;
    efa[e][c] = (c < 16) ? ef[(e0 + e) * EAA + c] : ea[(e0 + e) * EAA + (c - 16)];
  }
  __syncthreads();
  float wcol[32];
#pragma unroll
  for (int c = 0; c < 32; ++c) wcol[c] = Wem[(256 + c) * HH + j];
#pragma unroll
  for (int e = 0; e < EPB; ++e) {
    int s = src[e0 + e], d = dst[e0 + e];
    float acc = V1[s * HH + j] + V2[d * HH + j];
#pragma unroll
    for (int c = 0; c < 32; ++c) acc += efa[e][c] * wcol[c];
    em[e][j] = tanhf(acc);
  }
  __syncthreads();
  int k = j & 63, half = j >> 6;
  float a0 = 0.f, a1 = 0.f, a2 = 0.f, a3 = 0.f;
  for (int f = 0; f < HH; f += 4) {
    float4 m0 = *(const float4*)&em[half + 0][f];
    float4 m1 = *(const float4*)&em[half + 2][f];
    float4 m2 = *(const float4*)&em[half + 4][f];
    float4 m3 = *(const float4*)&em[half + 6][f];
    float w0 = Wproj[(f + 0) * KDIM + k], w1 = Wproj[(f + 1) * KDIM + k];
    float w2 = Wproj[(f + 2) * KDIM + k], w3 = Wproj[(f + 3) * KDIM + k];
    a0 += m0.x * w0 + m0.y * w1 + m0.z * w2 + m0.w * w3;
    a1 += m1.x * w0 + m1.y * w1 + m1.z * w2 + m1.w * w3;
    a2 += m2.x * w0 + m2.y * w1 + m2.z * w2 + m2.w * w3;
    a3 += m3.x * w0 + m3.y * w1 + m3.z * w2 + m3.w * w3;
  }
  hmsg[(e0 + half + 0) * KDIM + k] = a0;
  hmsg[(e0 + half + 2) * KDIM + k] = a1;
  hmsg[(e0 + half + 4) * KDIM + k] = a2;
  hmsg[(e0 + half + 6) * KDIM + k] = a3;
}

// ---- D7: edge blocks -> eblk (plain stores, no atomics) -------------------
#define EB2 4
__global__ __launch_bounds__(768) void k_edge_blk(
    const float* __restrict__ U, const float* __restrict__ hmsg,
    const int* __restrict__ src, const int* __restrict__ dst,
    const int* __restrict__ etype, const float* __restrict__ Wcomb,
    float* __restrict__ eblk) {
  int t = threadIdx.x;      // 0..191
  int ei = threadIdx.y;     // 0..3
  int e = blockIdx.x * EB2 + ei;
  int s = src[e], d = dst[e], p = etype[e];
  __shared__ __align__(16) float h[EB2][2][KDIM];
  __shared__ __align__(16) float tji[EB2][I_EDGE];
  if (t < 128) {
    int k = t & 63, w = t >> 6;      // w=0 -> ij, w=1 -> ji
    int a = w ? d : s, b = w ? s : d;
    h[ei][w][k] = hmsg[e * KDIM + k] + U[a * 128 + k] + U[b * 128 + 64 + k];
  }
  __syncthreads();
  float bij = 0.f, bji = 0.f;
  if (t < I_EDGE) {
    const float* W = Wcomb + p * KDIM * I_EDGE + t;
    for (int k = 0; k < KDIM; k += 4) {
      float4 hi = *(const float4*)&h[ei][0][k];
      float4 hj = *(const float4*)&h[ei][1][k];
      float w0 = W[(k + 0) * I_EDGE], w1 = W[(k + 1) * I_EDGE];
      float w2 = W[(k + 2) * I_EDGE], w3 = W[(k + 3) * I_EDGE];
      bij += hi.x * w0 + hi.y * w1 + hi.z * w2 + hi.w * w3;
      bji += hj.x * w0 + hj.y * w1 + hj.z * w2 + hj.w * w3;
    }
    tji[ei][t] = bji;
  }
  __syncthreads();
  if (t < I_EDGE) {
    int x = t / DD, y = t % DD;
    eblk[(size_t)e * I_EDGE + t] = 0.5f * (bij + tji[ei][y * DD + x]);
  }
}

// ---- D8: assemble M — LDS-accumulate per strip, ONE streaming pass --------
#define MAXS 72
__global__ __launch_bounds__(256) void k_assemble(
    const float* __restrict__ eblk, const float* __restrict__ nblk,
    const int* __restrict__ off, const int* __restrict__ adj,
    const int* __restrict__ src, const int* __restrict__ dst,
    float* __restrict__ M) {
  int n = blockIdx.x, t = threadIdx.x;
  __shared__ float blk[MAXS][I_EDGE];
  __shared__ signed char map8[13008];
  __shared__ int s_ed[MAXS];
  __shared__ short s_other[MAXS];
  int* map32 = (int*)map8;
  for (int i = t; i < 3252; i += 256) map32[i] = -1;
  int o0 = off[n], o1 = off[n + 1];
  int nent = 1 + (o1 - o0);                // entry 0 = diagonal block
  int ns = nent < MAXS ? nent : MAXS;
  for (int i = t; i < ns; i += 256) {
    int ed, other;
    if (i == 0) { ed = -1; other = n; }
    else { ed = adj[o0 + i - 1]; int e = ed >> 1; other = (ed & 1) ? src[e] : dst[e]; }
    s_ed[i] = ed; s_other[i] = (short)other;
  }
  __syncthreads();
  for (int j = t; j < ns * DD; j += 256) {       // winner-per-column map
    int i = j / DD, c = j - i * DD;
    map8[(int)s_other[i] * DD + c] = (signed char)i;
  }
  for (int j = t; j < ns * I_EDGE; j += 256) {   // gather blocks into LDS
    int i = j / I_EDGE, cell = j - i * I_EDGE;
    int ed = s_ed[i];
    float v;
    if (ed < 0)      v = nblk[n * I_EDGE + cell];
    else if (ed & 1) v = eblk[(size_t)(ed >> 1) * I_EDGE + (cell % DD) * DD + cell / DD];
    else             v = eblk[(size_t)(ed >> 1) * I_EDGE + cell];
    blk[i][cell] = v;
  }
  __syncthreads();
  for (int j = t; j < ns * I_EDGE; j += 256) {   // merge duplicate neighbors
    int i = j / I_EDGE, cell = j - i * I_EDGE;
    int cloc = cell % DD;
    int w = map8[(int)s_other[i] * DD + cloc];
    if (w != i) atomicAdd(&blk[w][cell], blk[i][cell]);
  }
  __syncthreads();
  float4* M4 = (float4*)M;
  for (int r = 0; r < DD; ++r) {                 // single streaming pass
    float4* rowp = M4 + (size_t)(n * DD + r) * ROW4;
    int rb = r * DD;
    for (int c4 = t; c4 < ROW4; c4 += 256) {
      int mp = map32[c4];
      float4 v = make_float4(0.f, 0.f, 0.f, 0.f);
      if (mp != -1) {
        int col = c4 * 4;
        signed char m0 = (signed char)(mp & 0xff);
        signed char m1 = (signed char)((mp >> 8) & 0xff);
        signed char m2 = (signed char)((mp >> 16) & 0xff);
        signed char m3 = (signed char)((mp >> 24) & 0xff);
        if (m0 >= 0) v.x = blk[m0][rb + (col + 0) % DD];
        if (m1 >= 0) v.y = blk[m1][rb + (col + 1) % DD];
        if (m2 >= 0) v.z = blk[m2][rb + (col + 2) % DD];
        if (m3 >= 0) v.w = blk[m3][rb + (col + 3) % DD];
      }
      rowp[c4] = v;
    }
  }
  if (nent > MAXS) {                             // overflow fallback (unused)
    __threadfence_block();
    __syncthreads();
    if (t < I_EDGE) {
      int x = t / DD, y = t - (t / DD) * DD;
      for (int i = MAXS; i < nent; ++i) {
        int ed = adj[o0 + i - 1]; int e = ed >> 1;
        int other = (ed & 1) ? src[e] : dst[e];
        float v = (ed & 1) ? eblk[(size_t)e * I_EDGE + y * DD + x]
                           : eblk[(size_t)e * I_EDGE + x * DD + y];
        M[(size_t)(n * DD + x) * MROW + other * DD + y] += v;
      }
    }
  }
}

extern "C" void kernel_launch(void* const* d_in, const int* in_sizes, int n_in,
                              void* d_out, int out_size, void* d_ws, size_t ws_size,
                              hipStream_t stream) {
  const float* node_feats = (const float*)d_in[0];
  const float* node_attrs = (const float*)d_in[1];
  const float* edge_feats = (const float*)d_in[2];
  const float* edge_attrs = (const float*)d_in[3];
  const int*   edge_index = (const int*)d_in[4];
  const int*   node_types = (const int*)d_in[5];
  const int*   edge_types = (const int*)d_in[6];
  const float* W_msg  = (const float*)d_in[7];
  const float* W_attr = (const float*)d_in[8];
  const float* W_em   = (const float*)d_in[9];
  const float* W_proj = (const float*)d_in[10];
  const float* W_node = (const float*)d_in[11];
  const float* W_edge = (const float*)d_in[12];
  const float* cob_node = (const float*)d_in[13];
  const float* cob_edge = (const float*)d_in[14];

  float* M  = (float*)d_out;
  float* ws = (float*)d_ws;
  float* m_buf = ws + WS_MBUF;
  float* hmsg  = ws + WS_HMSG;    // overlays m_buf region (m dead before D6)
  float* nblk  = ws + WS_NBLK;
  float* V1    = ws + WS_V1;
  float* V2    = ws + WS_V2;
  float* U     = ws + WS_U;
  float* Wcomb = ws + WS_WCOMB;
  float* Wnc   = ws + WS_WNC;
  int*   iw    = (int*)(ws + WS_INT);
  int*   cnt   = iw + IO_CNT;
  int*   off   = iw + IO_OFF;
  int*   cur   = iw + IO_CUR;
  int*   adj   = iw + IO_ADJ;
  float* eblk  = ws + WS_EBLK;

  const int* src = edge_index;        // edge_index[0]
  const int* dst = edge_index + EE;   // edge_index[1]

  k_front   <<<NB_FRONT, 256, 0, stream>>>(W_edge, cob_edge, W_node, cob_node,
                                           node_feats, W_msg, Wcomb, Wnc,
                                           m_buf, cnt);
  k_count   <<<(EE + 255) / 256, 256, 0, stream>>>(src, dst, cnt);
  k_scan    <<<1, 256, 0, stream>>>(cnt, off, cur);
  k_adj     <<<(EE + 255) / 256, 256, 0, stream>>>(src, dst, cur, adj);
  k_nodes   <<<NN, 192, 0, stream>>>(node_feats, m_buf, node_attrs, W_attr,
                                     W_em, W_proj, node_types, Wnc,
                                     off, adj, src, dst, V1, V2, U, nblk);
  k_edge_msg<<<EE / EPB, 128, 0, stream>>>(V1, V2, edge_feats, edge_attrs, src, dst,
                                           W_em, W_proj, hmsg);
  k_edge_blk<<<dim3(EE / EB2), dim3(192, 4), 0, stream>>>(U, hmsg, src, dst,
                                                          edge_types, Wcomb, eblk);
  k_assemble<<<NN, 256, 0, stream>>>(eblk, nblk, off, adj, src, dst, M);
}

// Round 7
// 917.418 us; speedup vs baseline: 1.1916x; 1.0226x over previous
//
#include <hip/hip_runtime.h>
#include <cmath>

#define NN   1000
#define TT   4
#define PP   10
#define DD   13
#define FF   128
#define HH   128
#define EAA  16
#define KDIM 64
#define EE   20000
#define I_NODE 91
#define I_EDGE 169
#define MROW  13000            // N*D
#define OUT_FLOAT4 42250000L   // 13000*13000/4

// ---- workspace layout (floats) --------------------------------------------
#define WS_M     0L            // m_buf   [N*F]
#define WS_AGG   128000L       // agg     [N*F]
#define WS_V1    256000L       // V1      [N*H]
#define WS_V2    384000L       // V2      [N*H]
#define WS_U     512000L       // U       [N*128]
#define WS_HMSG  640000L       // hmsg    [E*K]
#define WS_WCOMB 1920000L      // Wcomb   [P*K*169]
#define WS_WNC   2028160L      // Wnc     [T*F*169]  (end ~8.5 MB)

// ---- D1 "front": combs + node_msg + agg-zero, one dispatch ----------------
#define NB_CE   640
#define NB_CN   512
#define NB_MSG  1000
#define NB_FRONT (NB_CE + NB_CN + NB_MSG)

__global__ __launch_bounds__(256) void k_front(
    const float* __restrict__ We, const float* __restrict__ cobE,
    const float* __restrict__ Wn, const float* __restrict__ cobN,
    const float* __restrict__ nf, const float* __restrict__ Wmsg,
    float* __restrict__ Wcomb, float* __restrict__ Wnc,
    float* __restrict__ m, float* __restrict__ agg) {
  int b = blockIdx.x, t = threadIdx.x;
  if (b < NB_CE) {                       // comb_edge: Wcomb[p][k] = W_edge[p][k] @ cob_edge[p]
    if (t < I_EDGE) {
      int pk = b, p = pk >> 6;
      float acc = 0.f;
      const float* wrow = We + pk * I_EDGE;
      const float* crow = cobE + p * I_EDGE * I_EDGE + t;
      for (int i = 0; i < I_EDGE; ++i) acc += wrow[i] * crow[i * I_EDGE];
      Wcomb[pk * I_EDGE + t] = acc;
    }
  } else if (b < NB_CE + NB_CN) {        // comb_node
    if (t < I_EDGE) {
      int tf = b - NB_CE, ty = tf >> 7;
      float acc = 0.f;
      const float* wrow = Wn + tf * I_NODE;
      const float* crow = cobN + ty * I_NODE * I_EDGE + t;
      for (int i = 0; i < I_NODE; ++i) acc += wrow[i] * crow[i * I_EDGE];
      Wnc[tf * I_EDGE + t] = acc;
    }
  } else {                               // node_msg + agg zero
    int n = b - (NB_CE + NB_CN);
    __shared__ float row[FF];
    if (t < FF) row[t] = nf[n * FF + t];
    __syncthreads();
    if (t < FF) {
      float acc = 0.f;
#pragma unroll 8
      for (int f = 0; f < FF; ++f) acc += row[f] * Wmsg[f * FF + t];
      m[n * FF + t] = acc;
    } else {
      agg[n * FF + (t - FF)] = 0.f;
    }
  }
}

// ---- D2: zero-M (HBM stream) OVERLAPPED with agg atomic scatter (L2) ------
// The two roles are disjoint in data (M vs m/agg) and in resource
// (HBM store BW vs L2 atomic ops) -> the 676MB zero's bandwidth shadow
// hides the scatter instead of serializing as a separate dispatch.
#define NB_Z 8192
#define NB_SC ((EE * FF) / 256)

__global__ __launch_bounds__(256) void k_zero_scatter(
    float4* __restrict__ Mz, const float* __restrict__ m,
    const int* __restrict__ src, const int* __restrict__ dst,
    float* __restrict__ agg) {
  int b = blockIdx.x, t = threadIdx.x;
  if (b < NB_Z) {                        // zero output matrix (grid-stride)
    long base = (long)b * 256 + t;
    const long stride = (long)NB_Z * 256;
    const float4 z = make_float4(0.f, 0.f, 0.f, 0.f);
    for (long i = base; i < OUT_FLOAT4; i += stride) Mz[i] = z;
  } else {                               // symmetric segment sum via atomics
    int idx = (b - NB_Z) * 256 + t;
    int e = idx >> 7, j = idx & 127;
    int s = src[e], d = dst[e];
    atomicAdd(&agg[d * FF + j], m[s * FF + j]);
    atomicAdd(&agg[s * FF + j], m[d * FF + j]);
  }
}

// ---- D3: node_h + V1/V2/U precomputes + diagonal block (atomic into M) ----
__global__ __launch_bounds__(192) void k_nodes(
    const float* __restrict__ nf, const float* __restrict__ agg,
    const float* __restrict__ na, const float* __restrict__ Wattr,
    const float* __restrict__ Wem, const float* __restrict__ Wproj,
    const int* __restrict__ ntype, const float* __restrict__ Wnc,
    float* __restrict__ V1, float* __restrict__ V2, float* __restrict__ U,
    float* __restrict__ M) {
  int n = blockIdx.x, t = threadIdx.x;
  int ty = ntype[n];
  __shared__ float row[FF];
  if (t < FF) {
    float a = 0.f;
#pragma unroll
    for (int q = 0; q < TT; ++q) a += na[n * TT + q] * Wattr[q * FF + t];
    row[t] = nf[n * FF + t] + agg[n * FF + t] * (1.0f / 20.0f) + a;
  }
  __syncthreads();
  if (t < FF) {
    float v1 = 0.f, v2 = 0.f;
#pragma unroll 4
    for (int f = 0; f < FF; ++f) {
      float x = row[f];
      v1 += x * Wem[f * HH + t];
      v2 += x * Wem[(FF + f) * HH + t];
    }
    V1[n * HH + t] = v1;
    V2[n * HH + t] = v2;
    int k = t & 63, half = t >> 6;
    const float* W = Wproj + (FF + half * FF) * KDIM + k;
    float u = 0.f;
#pragma unroll 4
    for (int f = 0; f < FF; ++f) u += row[f] * W[f * KDIM];
    U[n * 128 + t] = u;
  }
  if (t < I_EDGE) {
    float acc = 0.f;
    const float* W = Wnc + ty * FF * I_EDGE + t;
#pragma unroll 4
    for (int f = 0; f < FF; ++f) acc += row[f] * W[f * I_EDGE];
    int x = t / DD, y = t % DD;
    atomicAdd(&M[(size_t)(n * DD + x) * MROW + (n * DD + y)], acc);
  }
}

// ---- D4: edge message + msg-projection (proven R2 kernel, unchanged) ------
#define EPB 8
__global__ __launch_bounds__(128) void k_edge_msg(
    const float* __restrict__ V1, const float* __restrict__ V2,
    const float* __restrict__ ef, const float* __restrict__ ea,
    const int* __restrict__ src, const int* __restrict__ dst,
    const float* __restrict__ Wem, const float* __restrict__ Wproj,
    float* __restrict__ hmsg) {
  int e0 = blockIdx.x * EPB;
  int j = threadIdx.x;
  __shared__ float efa[EPB][32];
  __shared__ float em[EPB][HH];
  for (int i = j; i < EPB * 32; i += 128) {
    int e = i >> 5, c = i & 31;
    efa[e][c] = (c < 16) ? ef[(e0 + e) * EAA + c] : ea[(e0 + e) * EAA + (c - 16)];
  }
  __syncthreads();
  float wcol[32];
#pragma unroll
  for (int c = 0; c < 32; ++c) wcol[c] = Wem[(256 + c) * HH + j];
#pragma unroll
  for (int e = 0; e < EPB; ++e) {
    int s = src[e0 + e], d = dst[e0 + e];
    float acc = V1[s * HH + j] + V2[d * HH + j];
#pragma unroll
    for (int c = 0; c < 32; ++c) acc += efa[e][c] * wcol[c];
    em[e][j] = tanhf(acc);
  }
  __syncthreads();
  int k = j & 63, half = j >> 6;
  float a0 = 0.f, a1 = 0.f, a2 = 0.f, a3 = 0.f;
  for (int f = 0; f < HH; f += 4) {
    float4 m0 = *(const float4*)&em[half + 0][f];
    float4 m1 = *(const float4*)&em[half + 2][f];
    float4 m2 = *(const float4*)&em[half + 4][f];
    float4 m3 = *(const float4*)&em[half + 6][f];
    float w0 = Wproj[(f + 0) * KDIM + k], w1 = Wproj[(f + 1) * KDIM + k];
    float w2 = Wproj[(f + 2) * KDIM + k], w3 = Wproj[(f + 3) * KDIM + k];
    a0 += m0.x * w0 + m0.y * w1 + m0.z * w2 + m0.w * w3;
    a1 += m1.x * w0 + m1.y * w1 + m1.z * w2 + m1.w * w3;
    a2 += m2.x * w0 + m2.y * w1 + m2.z * w2 + m2.w * w3;
    a3 += m3.x * w0 + m3.y * w1 + m3.z * w2 + m3.w * w3;
  }
  hmsg[(e0 + half + 0) * KDIM + k] = a0;
  hmsg[(e0 + half + 2) * KDIM + k] = a1;
  hmsg[(e0 + half + 4) * KDIM + k] = a2;
  hmsg[(e0 + half + 6) * KDIM + k] = a3;
}

// ---- D5: edge blocks, atomic scatter into M (proven R2 kernel) ------------
#define EB2 4
__global__ __launch_bounds__(768) void k_edge_blk(
    const float* __restrict__ U, const float* __restrict__ hmsg,
    const int* __restrict__ src, const int* __restrict__ dst,
    const int* __restrict__ etype, const float* __restrict__ Wcomb,
    float* __restrict__ M) {
  int t = threadIdx.x;      // 0..191
  int ei = threadIdx.y;     // 0..3
  int e = blockIdx.x * EB2 + ei;
  int s = src[e], d = dst[e], p = etype[e];
  __shared__ __align__(16) float h[EB2][2][KDIM];
  __shared__ __align__(16) float tji[EB2][I_EDGE];
  if (t < 128) {
    int k = t & 63, w = t >> 6;      // w=0 -> ij, w=1 -> ji
    int a = w ? d : s, b = w ? s : d;
    h[ei][w][k] = hmsg[e * KDIM + k] + U[a * 128 + k] + U[b * 128 + 64 + k];
  }
  __syncthreads();
  float bij = 0.f, bji = 0.f;
  if (t < I_EDGE) {
    const float* W = Wcomb + p * KDIM * I_EDGE + t;
    for (int k = 0; k < KDIM; k += 4) {
      float4 hi = *(const float4*)&h[ei][0][k];
      float4 hj = *(const float4*)&h[ei][1][k];
      float w0 = W[(k + 0) * I_EDGE], w1 = W[(k + 1) * I_EDGE];
      float w2 = W[(k + 2) * I_EDGE], w3 = W[(k + 3) * I_EDGE];
      bij += hi.x * w0 + hi.y * w1 + hi.z * w2 + hi.w * w3;
      bji += hj.x * w0 + hj.y * w1 + hj.z * w2 + hj.w * w3;
    }
    tji[ei][t] = bji;
  }
  __syncthreads();
  if (t < I_EDGE) {
    int x = t / DD, y = t % DD;
    float eb = 0.5f * (bij + tji[ei][y * DD + x]);
    atomicAdd(&M[(size_t)(s * DD + x) * MROW + (d * DD + y)], eb);
    atomicAdd(&M[(size_t)(d * DD + y) * MROW + (s * DD + x)], eb);
  }
}

extern "C" void kernel_launch(void* const* d_in, const int* in_sizes, int n_in,
                              void* d_out, int out_size, void* d_ws, size_t ws_size,
                              hipStream_t stream) {
  const float* node_feats = (const float*)d_in[0];
  const float* node_attrs = (const float*)d_in[1];
  const float* edge_feats = (const float*)d_in[2];
  const float* edge_attrs = (const float*)d_in[3];
  const int*   edge_index = (const int*)d_in[4];
  const int*   node_types = (const int*)d_in[5];
  const int*   edge_types = (const int*)d_in[6];
  const float* W_msg  = (const float*)d_in[7];
  const float* W_attr = (const float*)d_in[8];
  const float* W_em   = (const float*)d_in[9];
  const float* W_proj = (const float*)d_in[10];
  const float* W_node = (const float*)d_in[11];
  const float* W_edge = (const float*)d_in[12];
  const float* cob_node = (const float*)d_in[13];
  const float* cob_edge = (const float*)d_in[14];

  float* M  = (float*)d_out;
  float* ws = (float*)d_ws;
  float* m_buf = ws + WS_M;
  float* agg   = ws + WS_AGG;
  float* V1    = ws + WS_V1;
  float* V2    = ws + WS_V2;
  float* U     = ws + WS_U;
  float* hmsg  = ws + WS_HMSG;
  float* Wcomb = ws + WS_WCOMB;
  float* Wnc   = ws + WS_WNC;

  const int* src = edge_index;        // edge_index[0]
  const int* dst = edge_index + EE;   // edge_index[1]

  k_front       <<<NB_FRONT, 256, 0, stream>>>(W_edge, cob_edge, W_node, cob_node,
                                               node_feats, W_msg, Wcomb, Wnc,
                                               m_buf, agg);
  k_zero_scatter<<<NB_Z + NB_SC, 256, 0, stream>>>((float4*)M, m_buf, src, dst, agg);
  k_nodes       <<<NN, 192, 0, stream>>>(node_feats, agg, node_attrs, W_attr,
                                         W_em, W_proj, node_types, Wnc,
                                         V1, V2, U, M);
  k_edge_msg    <<<EE / EPB, 128, 0, stream>>>(V1, V2, edge_feats, edge_attrs,
                                               src, dst, W_em, W_proj, hmsg);
  k_edge_blk    <<<dim3(EE / EB2), dim3(192, 4), 0, stream>>>(U, hmsg, src, dst,
                                                              edge_types, Wcomb, M);
}